// Round 4
// baseline (553.107 us; speedup 1.0000x reference)
//
#include <hip/hip_runtime.h>
#include <hip/hip_bf16.h>

typedef _Float16 f16x8 __attribute__((ext_vector_type(8)));
typedef unsigned short u16x8 __attribute__((ext_vector_type(8)));
typedef float f32x4 __attribute__((ext_vector_type(4)));
typedef unsigned int u32x4 __attribute__((ext_vector_type(4)));

static __device__ __forceinline__ unsigned short h2u(_Float16 h) {
    return __builtin_bit_cast(unsigned short, h);
}
static __device__ __forceinline__ float fast_tanh(float x) {
    float e = __expf(2.0f * x);
    return 1.0f - 2.0f / (e + 1.0f);
}

// ---------------- prep: weight conversion into workspace ----------------
// ws layout (bytes):
//   wlin_h : u16 [320][512]  @ 0        (327680)   W_lin^T fp16 hi
//   wlin_l : u16 [320][512]  @ 327680   (327680)   W_lin^T fp16 lo
//   wnlm   : f32 [255][256]  @ 655360   (261120)   masked W_nl f32
//   wnl_h  : u16 [255][256]  @ 916480   (130560)   masked W_nl fp16 hi
//   wnl_l  : u16 [255][256]  @ 1047040  (130560)   masked W_nl fp16 lo
//   wout_h : u16 [64][256]   @ 1177600  (32768)
//   wout_l : u16 [64][256]   @ 1210368  (32768)    total 1243136
__global__ void cascade_prep(const float* __restrict__ W_lin,
                             const float* __restrict__ W_nl,
                             const float* __restrict__ W_out,
                             unsigned short* __restrict__ wlin_h,
                             unsigned short* __restrict__ wlin_l,
                             float* __restrict__ wnlm,
                             unsigned short* __restrict__ wnl_h,
                             unsigned short* __restrict__ wnl_l,
                             unsigned short* __restrict__ wout_h,
                             unsigned short* __restrict__ wout_l) {
    int idx = blockIdx.x * blockDim.x + threadIdx.x;
    int stride = gridDim.x * blockDim.x;
    for (int i = idx; i < 320 * 512; i += stride) {
        int n = i >> 9, k = i & 511;
        float w = W_lin[k * 320 + n];
        _Float16 h = (_Float16)w;
        wlin_h[i] = h2u(h);
        wlin_l[i] = h2u((_Float16)(w - (float)h));
    }
    for (int i = idx; i < 255 * 256; i += stride) {
        int r = i >> 8, k = i & 255;
        float w = (k <= r) ? W_nl[i] : 0.0f;
        wnlm[i] = w;
        _Float16 h = (_Float16)w;
        wnl_h[i] = h2u(h);
        wnl_l[i] = h2u((_Float16)(w - (float)h));
    }
    for (int i = idx; i < 64 * 256; i += stride) {
        float w = W_out[i];
        _Float16 h = (_Float16)w;
        wout_h[i] = h2u(h);
        wout_l[i] = h2u((_Float16)(w - (float)h));
    }
}

// build fp16 h/l MFMA A-fragments (h in low 16, l in high 16) from packed LDS
static __device__ __forceinline__ void tha_frag16(const unsigned int* tha, int rr, int kbase,
                                                  f16x8* ah, f16x8* al) {
    int base = rr * 256 + kbase;
    int swz = (rr & 7) << 2;
    u32x4 a0 = *reinterpret_cast<const u32x4*>(&tha[base ^ swz]);
    u32x4 a1 = *reinterpret_cast<const u32x4*>(&tha[(base + 4) ^ swz]);
    u32x4 hx, lx;
    hx[0] = (a0[0] & 0xffffu) | (a0[1] << 16);
    hx[1] = (a0[2] & 0xffffu) | (a0[3] << 16);
    hx[2] = (a1[0] & 0xffffu) | (a1[1] << 16);
    hx[3] = (a1[2] & 0xffffu) | (a1[3] << 16);
    lx[0] = (a0[0] >> 16) | (a0[1] & 0xffff0000u);
    lx[1] = (a0[2] >> 16) | (a0[3] & 0xffff0000u);
    lx[2] = (a1[0] >> 16) | (a1[1] & 0xffff0000u);
    lx[3] = (a1[2] >> 16) | (a1[3] & 0xffff0000u);
    *ah = __builtin_bit_cast(f16x8, hx);
    *al = __builtin_bit_cast(f16x8, lx);
}

static __device__ __forceinline__ float dot8(const float th[8], const float* wr) {
    float4 w0 = *reinterpret_cast<const float4*>(wr);
    float4 w1 = *reinterpret_cast<const float4*>(wr + 4);
    float s0 = th[0] * w0.x + th[1] * w0.y + th[2] * w0.z + th[3] * w0.w;
    float s1 = th[4] * w1.x + th[5] * w1.y + th[6] * w1.z + th[7] * w1.w;
    return s0 + s1;
}

// ---------------- fused main kernel ----------------
// 1 wave (64 threads) per block, 16 batch rows per block.
// LDS: tha 16384 + vT_lin 2048 + vT_con 2048 = 20480 B -> 8 blocks/CU (2 waves/SIMD).
__global__ __launch_bounds__(64, 2) void cascade_fused(
    const float* __restrict__ x,
    const unsigned short* __restrict__ wlin_h,
    const unsigned short* __restrict__ wlin_l,
    const float* __restrict__ wnlm,
    const unsigned short* __restrict__ wnl_h,
    const unsigned short* __restrict__ wnl_l,
    const unsigned short* __restrict__ wout_h,
    const unsigned short* __restrict__ wout_l,
    float* __restrict__ out) {

    __shared__ unsigned int tha[16 * 256];   // packed f16 h|l tanh values, swizzled
    __shared__ float vT_lin[32 * 16];        // [window col][row]
    __shared__ float vT_con[32 * 16];        // [window col][row]

    const int l   = threadIdx.x;
    const int l15 = l & 15;      // MFMA frag row / serial batch row
    const int g   = l >> 4;      // 0..3: MFMA k-group / serial octant owner
    const long row0 = (long)blockIdx.x * 16;

    // ===== phase 0: x tile as fp16 h/l MFMA A-fragments (128 VGPRs) =====
    f16x8 xfh[16], xfl[16];
    {
        const float* xp = x + (row0 + l15) * 512 + g * 8;
        #pragma unroll
        for (int ks = 0; ks < 16; ++ks) {
            float4 p0 = *reinterpret_cast<const float4*>(xp + ks * 32);
            float4 p1 = *reinterpret_cast<const float4*>(xp + ks * 32 + 4);
            float av[8] = {p0.x, p0.y, p0.z, p0.w, p1.x, p1.y, p1.z, p1.w};
            f16x8 fh, fl;
            #pragma unroll
            for (int e = 0; e < 8; ++e) {
                _Float16 hh = (_Float16)av[e];
                fh[e] = hh;
                fl[e] = (_Float16)(av[e] - (float)hh);
            }
            xfh[ks] = fh;
            xfl[ks] = fl;
        }
    }

    float th_oct[8];
    #pragma unroll
    for (int i = 0; i < 8; ++i) th_oct[i] = 0.0f;   // avoid NaN*0 from garbage
    float lin_carry = 0.0f;

    // ===== neuron-block loop: 8 blocks of 32 neurons =====
    for (int b = 0; b < 8; ++b) {
        __syncthreads();   // prev serial tha writes / vT reads complete

        f32x4 accL[2], accC[2];
        #pragma unroll
        for (int n2 = 0; n2 < 2; ++n2) {
            accL[n2] = (f32x4){0.f, 0.f, 0.f, 0.f};
            accC[n2] = (f32x4){0.f, 0.f, 0.f, 0.f};
        }

        // --- lin window GEMM: cols [32b, 32b+32), K=512, fp16-split 3 products ---
        #pragma unroll
        for (int ks = 0; ks < 16; ++ks) {
            #pragma unroll
            for (int n2 = 0; n2 < 2; ++n2) {
                const size_t brow = (size_t)(b * 32 + n2 * 16 + l15) * 512 + ks * 32 + g * 8;
                f16x8 bh = __builtin_bit_cast(f16x8, *reinterpret_cast<const u16x8*>(wlin_h + brow));
                f16x8 bl = __builtin_bit_cast(f16x8, *reinterpret_cast<const u16x8*>(wlin_l + brow));
                accL[n2] = __builtin_amdgcn_mfma_f32_16x16x32_f16(xfh[ks], bh, accL[n2], 0, 0, 0);
                accL[n2] = __builtin_amdgcn_mfma_f32_16x16x32_f16(xfl[ks], bh, accL[n2], 0, 0, 0);
                accL[n2] = __builtin_amdgcn_mfma_f32_16x16x32_f16(xfh[ks], bl, accL[n2], 0, 0, 0);
            }
        }

        // --- inter-block contribution GEMM: K = 32b from tanh history ---
        for (int kc = 0; kc < b; ++kc) {
            f16x8 ah, al;
            tha_frag16(tha, l15, kc * 32 + g * 8, &ah, &al);
            #pragma unroll
            for (int n2 = 0; n2 < 2; ++n2) {
                const size_t wrow = (size_t)(b * 32 + n2 * 16 + l15 - 1) * 256 + kc * 32 + g * 8;
                f16x8 bh = __builtin_bit_cast(f16x8, *reinterpret_cast<const u16x8*>(wnl_h + wrow));
                f16x8 bl = __builtin_bit_cast(f16x8, *reinterpret_cast<const u16x8*>(wnl_l + wrow));
                accC[n2] = __builtin_amdgcn_mfma_f32_16x16x32_f16(ah, bh, accC[n2], 0, 0, 0);
                accC[n2] = __builtin_amdgcn_mfma_f32_16x16x32_f16(al, bh, accC[n2], 0, 0, 0);
                accC[n2] = __builtin_amdgcn_mfma_f32_16x16x32_f16(ah, bl, accC[n2], 0, 0, 0);
            }
        }

        // --- bounce D-frags -> [col][row] windows in LDS ---
        #pragma unroll
        for (int n2 = 0; n2 < 2; ++n2)
            #pragma unroll
            for (int j = 0; j < 4; ++j) {
                int c = n2 * 16 + l15;
                int rr = g * 4 + j;
                vT_lin[c * 16 + rr] = accL[n2][j];
                vT_con[c * 16 + rr] = accC[n2][j];
            }
        __syncthreads();
        if (b == 0) lin_carry = vT_lin[0 * 16 + l15];   // lin[:,0] for neuron 0

        // --- serial intra-block cascade: 32 steps, 4 lanes per batch row ---
        {   // u = 0 (j = 32b; for b=0: v = lin[0] + 1; masked weights make pa=0 anyway)
            const int j = b * 32;
            const int jm1 = (b == 0) ? 0 : (j - 1);
            const float* wr = wnlm + (size_t)jm1 * 256 + b * 32 + g * 8;
            float pa = dot8(th_oct, wr);
            pa += __shfl_xor(pa, 16, 64);
            pa += __shfl_xor(pa, 32, 64);
            float v = (b == 0 ? 0.0f : pa) + vT_con[0 * 16 + l15] + lin_carry + 1.0f;
            float tv = fast_tanh(v);
            if (g == 0) {
                th_oct[0] = tv;
                _Float16 hh = (_Float16)tv;
                _Float16 ll = (_Float16)(tv - (float)hh);
                tha[(l15 * 256 + j) ^ ((l15 & 7) << 2)] =
                    ((unsigned int)h2u(ll) << 16) | (unsigned int)h2u(hh);
            }
        }
        #pragma unroll
        for (int u = 1; u < 32; ++u) {
            const int j = b * 32 + u;
            const float* wr = wnlm + (size_t)(j - 1) * 256 + b * 32 + g * 8;
            float pa = dot8(th_oct, wr);
            pa += __shfl_xor(pa, 16, 64);
            pa += __shfl_xor(pa, 32, 64);
            float v = pa + vT_con[u * 16 + l15] + vT_lin[(u - 1) * 16 + l15] + 1.0f;
            float tv = fast_tanh(v);
            if (g == (u >> 3)) th_oct[u & 7] = tv;
            if (g == 0) {
                _Float16 hh = (_Float16)tv;
                _Float16 ll = (_Float16)(tv - (float)hh);
                tha[(l15 * 256 + j) ^ ((l15 & 7) << 2)] =
                    ((unsigned int)h2u(ll) << 16) | (unsigned int)h2u(hh);
            }
        }
        lin_carry = vT_lin[31 * 16 + l15];
    }

    __syncthreads();   // tha complete for stage 3

    // ===== stage 3: out = tanh @ W_out^T + lin_o + 1 =====
    #pragma unroll
    for (int n = 0; n < 4; ++n) {
        f32x4 acc = (f32x4){0.f, 0.f, 0.f, 0.f};
        // lin_o part (cols 256+16n..): 1-product fp16
        #pragma unroll
        for (int ks = 0; ks < 16; ++ks) {
            const size_t brow = (size_t)(256 + n * 16 + l15) * 512 + ks * 32 + g * 8;
            f16x8 bh = __builtin_bit_cast(f16x8, *reinterpret_cast<const u16x8*>(wlin_h + brow));
            acc = __builtin_amdgcn_mfma_f32_16x16x32_f16(xfh[ks], bh, acc, 0, 0, 0);
        }
        // tanh @ W_out: K=256, fp16-split 3 products
        #pragma unroll
        for (int kc = 0; kc < 8; ++kc) {
            f16x8 ah, al;
            tha_frag16(tha, l15, kc * 32 + g * 8, &ah, &al);
            const size_t wrow = (size_t)(n * 16 + l15) * 256 + kc * 32 + g * 8;
            f16x8 bh = __builtin_bit_cast(f16x8, *reinterpret_cast<const u16x8*>(wout_h + wrow));
            f16x8 bl = __builtin_bit_cast(f16x8, *reinterpret_cast<const u16x8*>(wout_l + wrow));
            acc = __builtin_amdgcn_mfma_f32_16x16x32_f16(ah, bh, acc, 0, 0, 0);
            acc = __builtin_amdgcn_mfma_f32_16x16x32_f16(al, bh, acc, 0, 0, 0);
            acc = __builtin_amdgcn_mfma_f32_16x16x32_f16(ah, bl, acc, 0, 0, 0);
        }
        #pragma unroll
        for (int j = 0; j < 4; ++j)
            out[(row0 + g * 4 + j) * 64 + n * 16 + l15] = acc[j] + 1.0f;
    }
}

extern "C" void kernel_launch(void* const* d_in, const int* in_sizes, int n_in,
                              void* d_out, int out_size, void* d_ws, size_t ws_size,
                              hipStream_t stream) {
    (void)in_sizes; (void)n_in; (void)out_size; (void)ws_size;
    const float* x     = (const float*)d_in[0];
    const float* W_lin = (const float*)d_in[1];
    const float* W_nl  = (const float*)d_in[2];
    const float* W_out = (const float*)d_in[3];
    float* out = (float*)d_out;

    char* ws = (char*)d_ws;
    unsigned short* wlin_h = (unsigned short*)(ws);
    unsigned short* wlin_l = (unsigned short*)(ws + 327680);
    float*          wnlm   = (float*)(ws + 655360);
    unsigned short* wnl_h  = (unsigned short*)(ws + 916480);
    unsigned short* wnl_l  = (unsigned short*)(ws + 1047040);
    unsigned short* wout_h = (unsigned short*)(ws + 1177600);
    unsigned short* wout_l = (unsigned short*)(ws + 1210368);

    cascade_prep<<<256, 256, 0, stream>>>(W_lin, W_nl, W_out,
                                          wlin_h, wlin_l, wnlm, wnl_h, wnl_l,
                                          wout_h, wout_l);
    cascade_fused<<<65536 / 16, 64, 0, stream>>>(x, wlin_h, wlin_l, wnlm,
                                                 wnl_h, wnl_l, wout_h, wout_l, out);
}

// Round 5
// 520.599 us; speedup vs baseline: 1.0624x; 1.0624x over previous
//
#include <hip/hip_runtime.h>
#include <hip/hip_bf16.h>

typedef _Float16 f16x8 __attribute__((ext_vector_type(8)));
typedef unsigned short u16x8 __attribute__((ext_vector_type(8)));
typedef float f32x4 __attribute__((ext_vector_type(4)));
typedef unsigned int u32x4 __attribute__((ext_vector_type(4)));

static __device__ __forceinline__ unsigned short h2u(_Float16 h) {
    return __builtin_bit_cast(unsigned short, h);
}
static __device__ __forceinline__ float fast_tanh(float x) {
    float e = __expf(2.0f * x);
    return 1.0f - 2.0f / (e + 1.0f);
}

// ---------------- prep: weight conversion into workspace ----------------
// ws layout (bytes):
//   wlin_h : u16 [320][512]  @ 0        (327680)   W_lin^T fp16 hi
//   wlin_l : u16 [320][512]  @ 327680   (327680)   W_lin^T fp16 lo
//   wnlm   : f32 [255][256]  @ 655360   (261120)   masked W_nl f32
//   wnl_h  : u16 [255][256]  @ 916480   (130560)   masked W_nl fp16 hi
//   wnl_l  : u16 [255][256]  @ 1047040  (130560)   masked W_nl fp16 lo
//   wout_h : u16 [64][256]   @ 1177600  (32768)
//   wout_l : u16 [64][256]   @ 1210368  (32768)    total 1243136
__global__ void cascade_prep(const float* __restrict__ W_lin,
                             const float* __restrict__ W_nl,
                             const float* __restrict__ W_out,
                             unsigned short* __restrict__ wlin_h,
                             unsigned short* __restrict__ wlin_l,
                             float* __restrict__ wnlm,
                             unsigned short* __restrict__ wnl_h,
                             unsigned short* __restrict__ wnl_l,
                             unsigned short* __restrict__ wout_h,
                             unsigned short* __restrict__ wout_l) {
    int idx = blockIdx.x * blockDim.x + threadIdx.x;
    int stride = gridDim.x * blockDim.x;
    for (int i = idx; i < 320 * 512; i += stride) {
        int n = i >> 9, k = i & 511;
        float w = W_lin[k * 320 + n];
        _Float16 h = (_Float16)w;
        wlin_h[i] = h2u(h);
        wlin_l[i] = h2u((_Float16)(w - (float)h));
    }
    for (int i = idx; i < 255 * 256; i += stride) {
        int r = i >> 8, k = i & 255;
        float w = (k <= r) ? W_nl[i] : 0.0f;
        wnlm[i] = w;
        _Float16 h = (_Float16)w;
        wnl_h[i] = h2u(h);
        wnl_l[i] = h2u((_Float16)(w - (float)h));
    }
    for (int i = idx; i < 64 * 256; i += stride) {
        float w = W_out[i];
        _Float16 h = (_Float16)w;
        wout_h[i] = h2u(h);
        wout_l[i] = h2u((_Float16)(w - (float)h));
    }
}

// build fp16 h/l MFMA A-fragments (h in low 16, l in high 16) from packed LDS
static __device__ __forceinline__ void tha_frag16(const unsigned int* tha, int rr, int kbase,
                                                  f16x8* ah, f16x8* al) {
    int base = rr * 256 + kbase;
    int swz = (rr & 7) << 2;
    u32x4 a0 = *reinterpret_cast<const u32x4*>(&tha[base ^ swz]);
    u32x4 a1 = *reinterpret_cast<const u32x4*>(&tha[(base + 4) ^ swz]);
    u32x4 hx, lx;
    hx[0] = (a0[0] & 0xffffu) | (a0[1] << 16);
    hx[1] = (a0[2] & 0xffffu) | (a0[3] << 16);
    hx[2] = (a1[0] & 0xffffu) | (a1[1] << 16);
    hx[3] = (a1[2] & 0xffffu) | (a1[3] << 16);
    lx[0] = (a0[0] >> 16) | (a0[1] & 0xffff0000u);
    lx[1] = (a0[2] >> 16) | (a0[3] & 0xffff0000u);
    lx[2] = (a1[0] >> 16) | (a1[1] & 0xffff0000u);
    lx[3] = (a1[2] >> 16) | (a1[3] & 0xffff0000u);
    *ah = __builtin_bit_cast(f16x8, hx);
    *al = __builtin_bit_cast(f16x8, lx);
}

// ---------------- fused main kernel ----------------
// 1 wave (64 threads) per block, 16 batch rows per block.
// LDS: tha 16384 + vT_lin 2048 + vT_con 2048 = 20480 B -> 8 blocks/CU (2 waves/SIMD).
// Serial phase: lane l handles batch row (l&15) (lanes 16-63 replicate, wave-uniform);
// block-local tanh history lives in 32 registers; weights arrive via scalar loads
// (wave-uniform address -> s_load, SGPR operand in v_fma) so the dependence chain
// has NO cross-lane ops and NO VMEM.
__global__ __launch_bounds__(64, 2) void cascade_fused(
    const float* __restrict__ x,
    const unsigned short* __restrict__ wlin_h,
    const unsigned short* __restrict__ wlin_l,
    const float* __restrict__ wnlm,
    const unsigned short* __restrict__ wnl_h,
    const unsigned short* __restrict__ wnl_l,
    const unsigned short* __restrict__ wout_h,
    const unsigned short* __restrict__ wout_l,
    float* __restrict__ out) {

    __shared__ unsigned int tha[16 * 256];   // packed f16 h|l tanh values, swizzled
    __shared__ float vT_lin[32 * 16];        // [window col][row]
    __shared__ float vT_con[32 * 16];        // [window col][row]

    const int l   = threadIdx.x;
    const int l15 = l & 15;      // MFMA frag row / serial batch row
    const int g   = l >> 4;      // 0..3: MFMA k-group
    const long row0 = (long)blockIdx.x * 16;

    // ===== phase 0: x tile as fp16 h/l MFMA A-fragments (128 VGPRs) =====
    f16x8 xfh[16], xfl[16];
    {
        const float* xp = x + (row0 + l15) * 512 + g * 8;
        #pragma unroll
        for (int ks = 0; ks < 16; ++ks) {
            float4 p0 = *reinterpret_cast<const float4*>(xp + ks * 32);
            float4 p1 = *reinterpret_cast<const float4*>(xp + ks * 32 + 4);
            float av[8] = {p0.x, p0.y, p0.z, p0.w, p1.x, p1.y, p1.z, p1.w};
            f16x8 fh, fl;
            #pragma unroll
            for (int e = 0; e < 8; ++e) {
                _Float16 hh = (_Float16)av[e];
                fh[e] = hh;
                fl[e] = (_Float16)(av[e] - (float)hh);
            }
            xfh[ks] = fh;
            xfl[ks] = fl;
        }
    }

    float lin_carry = 0.0f;

    // ===== neuron-block loop: 8 blocks of 32 neurons =====
    for (int b = 0; b < 8; ++b) {
        __syncthreads();   // prev serial tha writes / vT reads complete

        f32x4 accL[2], accC[2];
        #pragma unroll
        for (int n2 = 0; n2 < 2; ++n2) {
            accL[n2] = (f32x4){0.f, 0.f, 0.f, 0.f};
            accC[n2] = (f32x4){0.f, 0.f, 0.f, 0.f};
        }

        // --- lin window GEMM: cols [32b, 32b+32), K=512, fp16-split 3 products ---
        #pragma unroll
        for (int ks = 0; ks < 16; ++ks) {
            #pragma unroll
            for (int n2 = 0; n2 < 2; ++n2) {
                const size_t brow = (size_t)(b * 32 + n2 * 16 + l15) * 512 + ks * 32 + g * 8;
                f16x8 bh = __builtin_bit_cast(f16x8, *reinterpret_cast<const u16x8*>(wlin_h + brow));
                f16x8 bl = __builtin_bit_cast(f16x8, *reinterpret_cast<const u16x8*>(wlin_l + brow));
                accL[n2] = __builtin_amdgcn_mfma_f32_16x16x32_f16(xfh[ks], bh, accL[n2], 0, 0, 0);
                accL[n2] = __builtin_amdgcn_mfma_f32_16x16x32_f16(xfl[ks], bh, accL[n2], 0, 0, 0);
                accL[n2] = __builtin_amdgcn_mfma_f32_16x16x32_f16(xfh[ks], bl, accL[n2], 0, 0, 0);
            }
        }

        // --- inter-block contribution GEMM: K = 32b from tanh history ---
        for (int kc = 0; kc < b; ++kc) {
            f16x8 ah, al;
            tha_frag16(tha, l15, kc * 32 + g * 8, &ah, &al);
            #pragma unroll
            for (int n2 = 0; n2 < 2; ++n2) {
                const size_t wrow = (size_t)(b * 32 + n2 * 16 + l15 - 1) * 256 + kc * 32 + g * 8;
                f16x8 bh = __builtin_bit_cast(f16x8, *reinterpret_cast<const u16x8*>(wnl_h + wrow));
                f16x8 bl = __builtin_bit_cast(f16x8, *reinterpret_cast<const u16x8*>(wnl_l + wrow));
                accC[n2] = __builtin_amdgcn_mfma_f32_16x16x32_f16(ah, bh, accC[n2], 0, 0, 0);
                accC[n2] = __builtin_amdgcn_mfma_f32_16x16x32_f16(al, bh, accC[n2], 0, 0, 0);
                accC[n2] = __builtin_amdgcn_mfma_f32_16x16x32_f16(ah, bl, accC[n2], 0, 0, 0);
            }
        }

        // --- bounce D-frags -> [col][row] windows in LDS ---
        #pragma unroll
        for (int n2 = 0; n2 < 2; ++n2)
            #pragma unroll
            for (int j = 0; j < 4; ++j) {
                int c = n2 * 16 + l15;
                int rr = g * 4 + j;
                vT_lin[c * 16 + rr] = accL[n2][j];
                vT_con[c * 16 + rr] = accC[n2][j];
            }
        __syncthreads();
        if (b == 0) lin_carry = vT_lin[0 * 16 + l15];   // lin[:,0] for neuron 0

        // --- serial intra-block cascade: 32 steps, 1 lane per row (x4 replicated) ---
        {
            float th[32];
            #pragma unroll
            for (int u = 0; u < 32; ++u) {
                const int j = b * 32 + u;
                // wave-uniform weight row pointer -> scalar loads (no loads when u==0)
                const float* wr = wnlm + (size_t)(j - 1) * 256 + b * 32;
                float p0 = 0.f, p1 = 0.f, p2 = 0.f, p3 = 0.f;
                #pragma unroll
                for (int c = 0; c + 3 < u; c += 4) {
                    p0 = fmaf(th[c],     wr[c],     p0);
                    p1 = fmaf(th[c + 1], wr[c + 1], p1);
                    p2 = fmaf(th[c + 2], wr[c + 2], p2);
                    p3 = fmaf(th[c + 3], wr[c + 3], p3);
                }
                #pragma unroll
                for (int c = u & ~3; c < u; ++c)
                    p0 = fmaf(th[c], wr[c], p0);
                float pa = (p0 + p1) + (p2 + p3);
                float lv = (u == 0) ? lin_carry : vT_lin[(u - 1) * 16 + l15];
                float v  = pa + vT_con[u * 16 + l15] + lv + 1.0f;
                float tv = fast_tanh(v);
                th[u] = tv;
                if (l < 16) {
                    _Float16 hh = (_Float16)tv;
                    _Float16 ll = (_Float16)(tv - (float)hh);
                    tha[(l15 * 256 + j) ^ ((l15 & 7) << 2)] =
                        ((unsigned int)h2u(ll) << 16) | (unsigned int)h2u(hh);
                }
            }
        }
        lin_carry = vT_lin[31 * 16 + l15];
    }

    __syncthreads();   // tha complete for stage 3

    // ===== stage 3: out = tanh @ W_out^T + lin_o + 1 =====
    #pragma unroll
    for (int n = 0; n < 4; ++n) {
        f32x4 acc = (f32x4){0.f, 0.f, 0.f, 0.f};
        // lin_o part (cols 256+16n..): 1-product fp16
        #pragma unroll
        for (int ks = 0; ks < 16; ++ks) {
            const size_t brow = (size_t)(256 + n * 16 + l15) * 512 + ks * 32 + g * 8;
            f16x8 bh = __builtin_bit_cast(f16x8, *reinterpret_cast<const u16x8*>(wlin_h + brow));
            acc = __builtin_amdgcn_mfma_f32_16x16x32_f16(xfh[ks], bh, acc, 0, 0, 0);
        }
        // tanh @ W_out: K=256, fp16-split 3 products
        #pragma unroll
        for (int kc = 0; kc < 8; ++kc) {
            f16x8 ah, al;
            tha_frag16(tha, l15, kc * 32 + g * 8, &ah, &al);
            const size_t wrow = (size_t)(n * 16 + l15) * 256 + kc * 32 + g * 8;
            f16x8 bh = __builtin_bit_cast(f16x8, *reinterpret_cast<const u16x8*>(wout_h + wrow));
            f16x8 bl = __builtin_bit_cast(f16x8, *reinterpret_cast<const u16x8*>(wout_l + wrow));
            acc = __builtin_amdgcn_mfma_f32_16x16x32_f16(ah, bh, acc, 0, 0, 0);
            acc = __builtin_amdgcn_mfma_f32_16x16x32_f16(al, bh, acc, 0, 0, 0);
            acc = __builtin_amdgcn_mfma_f32_16x16x32_f16(ah, bl, acc, 0, 0, 0);
        }
        #pragma unroll
        for (int j = 0; j < 4; ++j)
            out[(row0 + g * 4 + j) * 64 + n * 16 + l15] = acc[j] + 1.0f;
    }
}

extern "C" void kernel_launch(void* const* d_in, const int* in_sizes, int n_in,
                              void* d_out, int out_size, void* d_ws, size_t ws_size,
                              hipStream_t stream) {
    (void)in_sizes; (void)n_in; (void)out_size; (void)ws_size;
    const float* x     = (const float*)d_in[0];
    const float* W_lin = (const float*)d_in[1];
    const float* W_nl  = (const float*)d_in[2];
    const float* W_out = (const float*)d_in[3];
    float* out = (float*)d_out;

    char* ws = (char*)d_ws;
    unsigned short* wlin_h = (unsigned short*)(ws);
    unsigned short* wlin_l = (unsigned short*)(ws + 327680);
    float*          wnlm   = (float*)(ws + 655360);
    unsigned short* wnl_h  = (unsigned short*)(ws + 916480);
    unsigned short* wnl_l  = (unsigned short*)(ws + 1047040);
    unsigned short* wout_h = (unsigned short*)(ws + 1177600);
    unsigned short* wout_l = (unsigned short*)(ws + 1210368);

    cascade_prep<<<256, 256, 0, stream>>>(W_lin, W_nl, W_out,
                                          wlin_h, wlin_l, wnlm, wnl_h, wnl_l,
                                          wout_h, wout_l);
    cascade_fused<<<65536 / 16, 64, 0, stream>>>(x, wlin_h, wlin_l, wnlm,
                                                 wnl_h, wnl_l, wout_h, wout_l, out);
}

// Round 6
// 416.310 us; speedup vs baseline: 1.3286x; 1.2505x over previous
//
#include <hip/hip_runtime.h>
#include <hip/hip_bf16.h>

typedef _Float16 f16x8 __attribute__((ext_vector_type(8)));
typedef unsigned short u16x8 __attribute__((ext_vector_type(8)));
typedef float f32x4 __attribute__((ext_vector_type(4)));

static __device__ __forceinline__ unsigned short h2u(_Float16 h) {
    return __builtin_bit_cast(unsigned short, h);
}
static __device__ __forceinline__ float fast_tanh(float x) {
    float e = __expf(2.0f * x);
    return 1.0f - 2.0f / (e + 1.0f);
}

// ---------------- ws layout (bytes) ----------------
//   wlin_h : u16 [320][512]  @ 0        (327680)
//   wlin_l : u16 [320][512]  @ 327680   (327680)
//   wnlm   : f32 [255][256]  @ 655360   (261120)
//   wnl_h  : u16 [255][256]  @ 916480   (130560)
//   wnl_l  : u16 [255][256]  @ 1047040  (130560)
//   wout_h : u16 [64][256]   @ 1177600  (32768)
//   wout_l : u16 [64][256]   @ 1210368  (32768)
//   linc   : f32 [65536][256] @ 1243136 (67108864)
//   lino   : f32 [65536][64]  @ 68352000 (16777216)   total 85129216
__global__ void cascade_prep(const float* __restrict__ W_lin,
                             const float* __restrict__ W_nl,
                             const float* __restrict__ W_out,
                             unsigned short* __restrict__ wlin_h,
                             unsigned short* __restrict__ wlin_l,
                             float* __restrict__ wnlm,
                             unsigned short* __restrict__ wnl_h,
                             unsigned short* __restrict__ wnl_l,
                             unsigned short* __restrict__ wout_h,
                             unsigned short* __restrict__ wout_l) {
    int idx = blockIdx.x * blockDim.x + threadIdx.x;
    int stride = gridDim.x * blockDim.x;
    for (int i = idx; i < 320 * 512; i += stride) {
        int n = i >> 9, k = i & 511;
        float w = W_lin[k * 320 + n];
        _Float16 h = (_Float16)w;
        wlin_h[i] = h2u(h);
        wlin_l[i] = h2u((_Float16)(w - (float)h));
    }
    for (int i = idx; i < 255 * 256; i += stride) {
        int r = i >> 8, k = i & 255;
        float w = (k <= r) ? W_nl[i] : 0.0f;
        wnlm[i] = w;
        _Float16 h = (_Float16)w;
        wnl_h[i] = h2u(h);
        wnl_l[i] = h2u((_Float16)(w - (float)h));
    }
    for (int i = idx; i < 64 * 256; i += stride) {
        float w = W_out[i];
        _Float16 h = (_Float16)w;
        wout_h[i] = h2u(h);
        wout_l[i] = h2u((_Float16)(w - (float)h));
    }
}

// ---------------- kernel A: lin = x @ W_lin (fp16-split), writes linc/lino ----------------
// 256 threads, 32 rows/block. LDS x hi/lo [32][520] fp16 = 66560 B -> 2 blocks/CU.
__global__ __launch_bounds__(256, 2) void lin_gemm(
    const float* __restrict__ x,
    const unsigned short* __restrict__ wlin_h,
    const unsigned short* __restrict__ wlin_l,
    float* __restrict__ linc,
    float* __restrict__ lino) {

    __shared__ _Float16 xh[32 * 520];
    __shared__ _Float16 xl[32 * 520];

    const int tid = threadIdx.x;
    const int wv  = tid >> 6;
    const int l15 = tid & 15;
    const int g   = (tid & 63) >> 4;
    const long row0 = (long)blockIdx.x * 32;

    // stage x, split fp16 hi/lo
    #pragma unroll
    for (int it = 0; it < 16; ++it) {
        int flat = it * 1024 + tid * 4;      // 32*512 = 16384 floats
        int r = flat >> 9, c = flat & 511;
        float4 v = *reinterpret_cast<const float4*>(x + (row0 + r) * 512 + c);
        _Float16 h0 = (_Float16)v.x, h1 = (_Float16)v.y, h2 = (_Float16)v.z, h3 = (_Float16)v.w;
        ushort4 uh = { h2u(h0), h2u(h1), h2u(h2), h2u(h3) };
        ushort4 ul = { h2u((_Float16)(v.x - (float)h0)), h2u((_Float16)(v.y - (float)h1)),
                       h2u((_Float16)(v.z - (float)h2)), h2u((_Float16)(v.w - (float)h3)) };
        *reinterpret_cast<ushort4*>(xh + r * 520 + c) = uh;
        *reinterpret_cast<ushort4*>(xl + r * 520 + c) = ul;
    }
    __syncthreads();

    f32x4 acc[2][5];
    #pragma unroll
    for (int m = 0; m < 2; ++m)
        #pragma unroll
        for (int ti = 0; ti < 5; ++ti) acc[m][ti] = (f32x4){0.f, 0.f, 0.f, 0.f};

    for (int half = 0; half < 2; ++half) {
        f16x8 ah[2][8], al[2][8];
        #pragma unroll
        for (int m = 0; m < 2; ++m)
            #pragma unroll
            for (int k8 = 0; k8 < 8; ++k8) {
                int off = (m * 16 + l15) * 520 + g * 8 + (half * 8 + k8) * 32;
                ah[m][k8] = *reinterpret_cast<const f16x8*>(xh + off);
                al[m][k8] = *reinterpret_cast<const f16x8*>(xl + off);
            }
        #pragma unroll
        for (int ti = 0; ti < 5; ++ti) {
            int n = wv + ti * 4;
            const unsigned short* bhp = wlin_h + (size_t)(n * 16 + l15) * 512 + g * 8 + half * 256;
            const unsigned short* blp = wlin_l + (size_t)(n * 16 + l15) * 512 + g * 8 + half * 256;
            #pragma unroll
            for (int k8 = 0; k8 < 8; ++k8) {
                f16x8 bh = __builtin_bit_cast(f16x8, *reinterpret_cast<const u16x8*>(bhp + k8 * 32));
                #pragma unroll
                for (int m = 0; m < 2; ++m)
                    acc[m][ti] = __builtin_amdgcn_mfma_f32_16x16x32_f16(ah[m][k8], bh, acc[m][ti], 0, 0, 0);
                if (ti < 4) {
                    f16x8 bl = __builtin_bit_cast(f16x8, *reinterpret_cast<const u16x8*>(blp + k8 * 32));
                    #pragma unroll
                    for (int m = 0; m < 2; ++m) {
                        acc[m][ti] = __builtin_amdgcn_mfma_f32_16x16x32_f16(al[m][k8], bh, acc[m][ti], 0, 0, 0);
                        acc[m][ti] = __builtin_amdgcn_mfma_f32_16x16x32_f16(ah[m][k8], bl, acc[m][ti], 0, 0, 0);
                    }
                }
            }
        }
    }
    // write out: D col = l15, row = g*4+j
    #pragma unroll
    for (int m = 0; m < 2; ++m) {
        #pragma unroll
        for (int ti = 0; ti < 4; ++ti) {
            int c = (wv + ti * 4) * 16 + l15;
            #pragma unroll
            for (int j = 0; j < 4; ++j)
                linc[(row0 + m * 16 + g * 4 + j) * 256 + c] = acc[m][ti][j];
        }
        int c = wv * 16 + l15;
        #pragma unroll
        for (int j = 0; j < 4; ++j)
            lino[(row0 + m * 16 + g * 4 + j) * 64 + c] = acc[m][4][j];
    }
}

// ---------------- kernel B: cascade + output GEMM ----------------
// 1 wave, 16 rows/block. LDS: lhist 8448 + conT 2304 + linT 2304 = 13056 B
// -> 12 blocks/CU (3 waves/SIMD). Serial chain is register-only; lin/con come
// from LDS in 8-wide register windows; tanh history hi-half lives in VGPRs
// (each lane's MFMA A-frag row == its own serial row), lo-half in LDS.
__global__ __launch_bounds__(64, 3) void cascade_casc(
    const float* __restrict__ linc,
    const float* __restrict__ lino,
    const float* __restrict__ wnlm,
    const unsigned short* __restrict__ wnl_h,
    const unsigned short* __restrict__ wnl_l,
    const unsigned short* __restrict__ wout_h,
    const unsigned short* __restrict__ wout_l,
    float* __restrict__ out) {

    __shared__ unsigned short lhist[16 * 264];   // fp16 lo of tanh history
    __shared__ float conT[16 * 36];              // [row][u] contrib window (+scratch)
    __shared__ float linT[16 * 36];              // [row][u] lin window

    const int l   = threadIdx.x;
    const int l15 = l & 15;
    const int g   = l >> 4;
    const long row0 = (long)blockIdx.x * 16;

    f16x8 hh[8];        // fp16 hi history, lane's own (row, g-slice)
    float th[32];       // current block tanh, f32, replicated across g
    float carry = 0.0f;

    #pragma unroll
    for (int b = 0; b < 8; ++b) {
        // --- stage lin window [16 rows][32 cols] -> linT ---
        {
            int rr = l >> 2, c8 = (l & 3) * 8;
            const float* lp = linc + (row0 + rr) * 256 + b * 32 + c8;
            float4 v0 = *reinterpret_cast<const float4*>(lp);
            float4 v1 = *reinterpret_cast<const float4*>(lp + 4);
            *reinterpret_cast<float4*>(&linT[rr * 36 + c8]) = v0;
            *reinterpret_cast<float4*>(&linT[rr * 36 + c8 + 4]) = v1;
        }

        // --- inter-block contribution GEMM (K = 32b) ---
        f32x4 accC[2];
        accC[0] = (f32x4){0.f, 0.f, 0.f, 0.f};
        accC[1] = (f32x4){0.f, 0.f, 0.f, 0.f};
        #pragma unroll
        for (int kc = 0; kc < 7; ++kc) {
            if (kc < b) {
                f16x8 ah = hh[kc];
                f16x8 al = __builtin_bit_cast(f16x8,
                    *reinterpret_cast<const u16x8*>(&lhist[l15 * 264 + kc * 32 + g * 8]));
                #pragma unroll
                for (int n2 = 0; n2 < 2; ++n2) {
                    const size_t wrow = (size_t)(b * 32 + n2 * 16 + l15 - 1) * 256 + kc * 32 + g * 8;
                    f16x8 bh = __builtin_bit_cast(f16x8, *reinterpret_cast<const u16x8*>(wnl_h + wrow));
                    f16x8 bl = __builtin_bit_cast(f16x8, *reinterpret_cast<const u16x8*>(wnl_l + wrow));
                    accC[n2] = __builtin_amdgcn_mfma_f32_16x16x32_f16(ah, bh, accC[n2], 0, 0, 0);
                    accC[n2] = __builtin_amdgcn_mfma_f32_16x16x32_f16(al, bh, accC[n2], 0, 0, 0);
                    accC[n2] = __builtin_amdgcn_mfma_f32_16x16x32_f16(ah, bl, accC[n2], 0, 0, 0);
                }
            }
        }
        // bounce D-frags -> conT[row][col]
        #pragma unroll
        for (int n2 = 0; n2 < 2; ++n2)
            #pragma unroll
            for (int j = 0; j < 4; ++j)
                conT[(g * 4 + j) * 36 + n2 * 16 + l15] = accC[n2][j];
        __syncthreads();

        if (b == 0) carry = linT[l15 * 36];   // lin[row, 0] for neuron 0

        // --- serial 32 steps, operands in registers ---
        float lastlin = carry;
        #pragma unroll
        for (int u8 = 0; u8 < 4; ++u8) {
            float4 cw0 = *reinterpret_cast<const float4*>(&conT[l15 * 36 + u8 * 8]);
            float4 cw1 = *reinterpret_cast<const float4*>(&conT[l15 * 36 + u8 * 8 + 4]);
            float4 lw0 = *reinterpret_cast<const float4*>(&linT[l15 * 36 + u8 * 8]);
            float4 lw1 = *reinterpret_cast<const float4*>(&linT[l15 * 36 + u8 * 8 + 4]);
            float conw[8] = {cw0.x, cw0.y, cw0.z, cw0.w, cw1.x, cw1.y, cw1.z, cw1.w};
            float linw[8] = {lw0.x, lw0.y, lw0.z, lw0.w, lw1.x, lw1.y, lw1.z, lw1.w};
            #pragma unroll
            for (int v = 0; v < 8; ++v) {
                const int u = u8 * 8 + v;
                float pa = 0.0f;
                if (u > 0) {
                    const float* wr = wnlm + (size_t)(b * 32 + u - 1) * 256 + b * 32;
                    float p0 = 0.f, p1 = 0.f, p2 = 0.f, p3 = 0.f;
                    #pragma unroll
                    for (int c = 0; c + 3 < u; c += 4) {
                        p0 = fmaf(th[c],     wr[c],     p0);
                        p1 = fmaf(th[c + 1], wr[c + 1], p1);
                        p2 = fmaf(th[c + 2], wr[c + 2], p2);
                        p3 = fmaf(th[c + 3], wr[c + 3], p3);
                    }
                    #pragma unroll
                    for (int c = u & ~3; c < u; ++c)
                        p0 = fmaf(th[c], wr[c], p0);
                    pa = (p0 + p1) + (p2 + p3);
                }
                float lv = (v == 0) ? lastlin : linw[v - 1];
                float vv = pa + conw[v] + lv + 1.0f;
                th[u] = fast_tanh(vv);
            }
            lastlin = linw[7];
        }
        carry = lastlin;

        // --- pack history: th -> fp16 hi (regs) + lo (LDS) ---
        if (l < 16) {
            #pragma unroll
            for (int c8 = 0; c8 < 32; c8 += 4)
                *reinterpret_cast<float4*>(&conT[l15 * 36 + c8]) =
                    (float4){th[c8], th[c8 + 1], th[c8 + 2], th[c8 + 3]};
        }
        __syncthreads();
        float4 s0 = *reinterpret_cast<const float4*>(&conT[l15 * 36 + g * 8]);
        float4 s1 = *reinterpret_cast<const float4*>(&conT[l15 * 36 + g * 8 + 4]);
        float sv[8] = {s0.x, s0.y, s0.z, s0.w, s1.x, s1.y, s1.z, s1.w};
        f16x8 fh, fl;
        #pragma unroll
        for (int e = 0; e < 8; ++e) {
            _Float16 hv = (_Float16)sv[e];
            fh[e] = hv;
            fl[e] = (_Float16)(sv[e] - (float)hv);
        }
        hh[b] = fh;
        *reinterpret_cast<u16x8*>(&lhist[l15 * 264 + b * 32 + g * 8]) =
            __builtin_bit_cast(u16x8, fl);
        __syncthreads();
    }

    // ===== stage 3: out = tanh @ W_out^T + lin_o + 1 =====
    #pragma unroll
    for (int n = 0; n < 4; ++n) {
        f32x4 acc = (f32x4){0.f, 0.f, 0.f, 0.f};
        #pragma unroll
        for (int kc = 0; kc < 8; ++kc) {
            f16x8 ah = hh[kc];
            f16x8 al = __builtin_bit_cast(f16x8,
                *reinterpret_cast<const u16x8*>(&lhist[l15 * 264 + kc * 32 + g * 8]));
            const size_t wrow = (size_t)(n * 16 + l15) * 256 + kc * 32 + g * 8;
            f16x8 bh = __builtin_bit_cast(f16x8, *reinterpret_cast<const u16x8*>(wout_h + wrow));
            f16x8 bl = __builtin_bit_cast(f16x8, *reinterpret_cast<const u16x8*>(wout_l + wrow));
            acc = __builtin_amdgcn_mfma_f32_16x16x32_f16(ah, bh, acc, 0, 0, 0);
            acc = __builtin_amdgcn_mfma_f32_16x16x32_f16(al, bh, acc, 0, 0, 0);
            acc = __builtin_amdgcn_mfma_f32_16x16x32_f16(ah, bl, acc, 0, 0, 0);
        }
        #pragma unroll
        for (int j = 0; j < 4; ++j) {
            long r = row0 + g * 4 + j;
            int c = n * 16 + l15;
            out[r * 64 + c] = acc[j] + lino[r * 64 + c] + 1.0f;
        }
    }
}

extern "C" void kernel_launch(void* const* d_in, const int* in_sizes, int n_in,
                              void* d_out, int out_size, void* d_ws, size_t ws_size,
                              hipStream_t stream) {
    (void)in_sizes; (void)n_in; (void)out_size; (void)ws_size;
    const float* x     = (const float*)d_in[0];
    const float* W_lin = (const float*)d_in[1];
    const float* W_nl  = (const float*)d_in[2];
    const float* W_out = (const float*)d_in[3];
    float* out = (float*)d_out;

    char* ws = (char*)d_ws;
    unsigned short* wlin_h = (unsigned short*)(ws);
    unsigned short* wlin_l = (unsigned short*)(ws + 327680);
    float*          wnlm   = (float*)(ws + 655360);
    unsigned short* wnl_h  = (unsigned short*)(ws + 916480);
    unsigned short* wnl_l  = (unsigned short*)(ws + 1047040);
    unsigned short* wout_h = (unsigned short*)(ws + 1177600);
    unsigned short* wout_l = (unsigned short*)(ws + 1210368);
    float*          linc   = (float*)(ws + 1243136);
    float*          lino   = (float*)(ws + 68352000);

    cascade_prep<<<256, 256, 0, stream>>>(W_lin, W_nl, W_out,
                                          wlin_h, wlin_l, wnlm, wnl_h, wnl_l,
                                          wout_h, wout_l);
    lin_gemm<<<65536 / 32, 256, 0, stream>>>(x, wlin_h, wlin_l, linc, lino);
    cascade_casc<<<65536 / 16, 64, 0, stream>>>(linc, lino, wnlm,
                                                wnl_h, wnl_l, wout_h, wout_l, out);
}

// Round 7
// 340.529 us; speedup vs baseline: 1.6243x; 1.2225x over previous
//
#include <hip/hip_runtime.h>
#include <hip/hip_bf16.h>

typedef _Float16 f16x8 __attribute__((ext_vector_type(8)));
typedef unsigned short u16x8 __attribute__((ext_vector_type(8)));
typedef float f32x4 __attribute__((ext_vector_type(4)));

static __device__ __forceinline__ unsigned short h2u(_Float16 h) {
    return __builtin_bit_cast(unsigned short, h);
}
static __device__ __forceinline__ float fast_tanh(float x) {
    float e = __expf(2.0f * x);
    return 1.0f - 2.0f / (e + 1.0f);
}

// ---------------- ws layout (bytes) ----------------
//   wlin_h : u16 [320][512]   @ 0        (327680)
//   wlin_l : u16 [320][512]   @ 327680   (327680)
//   wnlm   : f32 [255][256]   @ 655360   (261120)
//   wnl_h  : u16 [255][256]   @ 916480   (130560)
//   wnl_l  : u16 [255][256]   @ 1047040  (130560)
//   wout_h : u16 [64][256]    @ 1177600  (32768)
//   wout_l : u16 [64][256]    @ 1210368  (32768)
//   wtri   : f32 [8][496]     @ 1243136  (15872)   compact intra-block triangles
//   linc   : f32 [65536][256] @ 1259008  (67108864)
//   lino   : f32 [65536][64]  @ 68367872 (16777216)  total 85145088
__global__ void cascade_prep(const float* __restrict__ W_lin,
                             const float* __restrict__ W_nl,
                             const float* __restrict__ W_out,
                             unsigned short* __restrict__ wlin_h,
                             unsigned short* __restrict__ wlin_l,
                             float* __restrict__ wnlm,
                             unsigned short* __restrict__ wnl_h,
                             unsigned short* __restrict__ wnl_l,
                             unsigned short* __restrict__ wout_h,
                             unsigned short* __restrict__ wout_l,
                             float* __restrict__ wtri) {
    int idx = blockIdx.x * blockDim.x + threadIdx.x;
    int stride = gridDim.x * blockDim.x;
    for (int i = idx; i < 320 * 512; i += stride) {
        int n = i >> 9, k = i & 511;
        float w = W_lin[k * 320 + n];
        _Float16 h = (_Float16)w;
        wlin_h[i] = h2u(h);
        wlin_l[i] = h2u((_Float16)(w - (float)h));
    }
    for (int i = idx; i < 255 * 256; i += stride) {
        int r = i >> 8, k = i & 255;
        float w = (k <= r) ? W_nl[i] : 0.0f;
        wnlm[i] = w;
        _Float16 h = (_Float16)w;
        wnl_h[i] = h2u(h);
        wnl_l[i] = h2u((_Float16)(w - (float)h));
    }
    for (int i = idx; i < 64 * 256; i += stride) {
        float w = W_out[i];
        _Float16 h = (_Float16)w;
        wout_h[i] = h2u(h);
        wout_l[i] = h2u((_Float16)(w - (float)h));
    }
    // compact intra-block triangular weights: wtri[b][u*(u-1)/2 + c] =
    // W_nl[(32b+u-1)*256 + 32b + c], u in [1,32), c < u  (mask trivially true)
    for (int i = idx; i < 256; i += stride) {
        int b = i >> 5, u = i & 31;
        if (u >= 1) {
            float* dst = wtri + b * 496 + (u * (u - 1)) / 2;
            const float* src = W_nl + (size_t)(b * 32 + u - 1) * 256 + b * 32;
            for (int c = 0; c < u; ++c) dst[c] = src[c];
        }
    }
}

// ---------------- kernel A: lin = x @ W_lin (fp16-split), writes linc/lino ----------------
// 256 threads, 32 rows/block. LDS x hi/lo [32][520] fp16 = 66560 B -> 2 blocks/CU.
__global__ __launch_bounds__(256, 2) void lin_gemm(
    const float* __restrict__ x,
    const unsigned short* __restrict__ wlin_h,
    const unsigned short* __restrict__ wlin_l,
    float* __restrict__ linc,
    float* __restrict__ lino) {

    __shared__ _Float16 xh[32 * 520];
    __shared__ _Float16 xl[32 * 520];

    const int tid = threadIdx.x;
    const int wv  = tid >> 6;
    const int l15 = tid & 15;
    const int g   = (tid & 63) >> 4;
    const long row0 = (long)blockIdx.x * 32;

    #pragma unroll
    for (int it = 0; it < 16; ++it) {
        int flat = it * 1024 + tid * 4;
        int r = flat >> 9, c = flat & 511;
        float4 v = *reinterpret_cast<const float4*>(x + (row0 + r) * 512 + c);
        _Float16 h0 = (_Float16)v.x, h1 = (_Float16)v.y, h2 = (_Float16)v.z, h3 = (_Float16)v.w;
        ushort4 uh = { h2u(h0), h2u(h1), h2u(h2), h2u(h3) };
        ushort4 ul = { h2u((_Float16)(v.x - (float)h0)), h2u((_Float16)(v.y - (float)h1)),
                       h2u((_Float16)(v.z - (float)h2)), h2u((_Float16)(v.w - (float)h3)) };
        *reinterpret_cast<ushort4*>(xh + r * 520 + c) = uh;
        *reinterpret_cast<ushort4*>(xl + r * 520 + c) = ul;
    }
    __syncthreads();

    f32x4 acc[2][5];
    #pragma unroll
    for (int m = 0; m < 2; ++m)
        #pragma unroll
        for (int ti = 0; ti < 5; ++ti) acc[m][ti] = (f32x4){0.f, 0.f, 0.f, 0.f};

    for (int half = 0; half < 2; ++half) {
        f16x8 ah[2][8], al[2][8];
        #pragma unroll
        for (int m = 0; m < 2; ++m)
            #pragma unroll
            for (int k8 = 0; k8 < 8; ++k8) {
                int off = (m * 16 + l15) * 520 + g * 8 + (half * 8 + k8) * 32;
                ah[m][k8] = *reinterpret_cast<const f16x8*>(xh + off);
                al[m][k8] = *reinterpret_cast<const f16x8*>(xl + off);
            }
        #pragma unroll
        for (int ti = 0; ti < 5; ++ti) {
            int n = wv + ti * 4;
            const unsigned short* bhp = wlin_h + (size_t)(n * 16 + l15) * 512 + g * 8 + half * 256;
            const unsigned short* blp = wlin_l + (size_t)(n * 16 + l15) * 512 + g * 8 + half * 256;
            #pragma unroll
            for (int k8 = 0; k8 < 8; ++k8) {
                f16x8 bh = __builtin_bit_cast(f16x8, *reinterpret_cast<const u16x8*>(bhp + k8 * 32));
                #pragma unroll
                for (int m = 0; m < 2; ++m)
                    acc[m][ti] = __builtin_amdgcn_mfma_f32_16x16x32_f16(ah[m][k8], bh, acc[m][ti], 0, 0, 0);
                if (ti < 4) {
                    f16x8 bl = __builtin_bit_cast(f16x8, *reinterpret_cast<const u16x8*>(blp + k8 * 32));
                    #pragma unroll
                    for (int m = 0; m < 2; ++m) {
                        acc[m][ti] = __builtin_amdgcn_mfma_f32_16x16x32_f16(al[m][k8], bh, acc[m][ti], 0, 0, 0);
                        acc[m][ti] = __builtin_amdgcn_mfma_f32_16x16x32_f16(ah[m][k8], bl, acc[m][ti], 0, 0, 0);
                    }
                }
            }
        }
    }
    #pragma unroll
    for (int m = 0; m < 2; ++m) {
        #pragma unroll
        for (int ti = 0; ti < 4; ++ti) {
            int c = (wv + ti * 4) * 16 + l15;
            #pragma unroll
            for (int j = 0; j < 4; ++j)
                linc[(row0 + m * 16 + g * 4 + j) * 256 + c] = acc[m][ti][j];
        }
        int c = wv * 16 + l15;
        #pragma unroll
        for (int j = 0; j < 4; ++j)
            lino[(row0 + m * 16 + g * 4 + j) * 64 + c] = acc[m][4][j];
    }
}

// ---------------- kernel B: cascade + output GEMM ----------------
// 1 wave, 16 rows/block. LDS: conT 2304 + linT 2304 = 4608 B.
// __launch_bounds__(64,4): 16 blocks/CU -> all 4096 waves resident in ONE round.
// History: fp16 hi AND lo both in registers (static indexing only).
__global__ __launch_bounds__(64, 4) void cascade_casc(
    const float* __restrict__ linc,
    const float* __restrict__ lino,
    const float* __restrict__ wtri,
    const unsigned short* __restrict__ wnl_h,
    const unsigned short* __restrict__ wnl_l,
    const unsigned short* __restrict__ wout_h,
    const unsigned short* __restrict__ wout_l,
    float* __restrict__ out) {

    __shared__ float conT[16 * 36];   // [row][u] contrib window / pack scratch
    __shared__ float linT[16 * 36];   // [row][u] lin window

    const int l   = threadIdx.x;
    const int l15 = l & 15;
    const int g   = l >> 4;
    const long row0 = (long)blockIdx.x * 16;

    f16x8 hh[8];   // fp16 hi history (lane's own row, g-slice) — static idx only
    f16x8 ll[8];   // fp16 lo history — static idx only
    float th[32];  // current block tanh f32 (replicated across g) — static idx only
    float carry = 0.0f;

    #pragma unroll
    for (int b = 0; b < 8; ++b) {
        // --- stage lin window [16 rows][32 cols] -> linT ---
        {
            int rr = l >> 2, c8 = (l & 3) * 8;
            const float* lp = linc + (row0 + rr) * 256 + b * 32 + c8;
            float4 v0 = *reinterpret_cast<const float4*>(lp);
            float4 v1 = *reinterpret_cast<const float4*>(lp + 4);
            *reinterpret_cast<float4*>(&linT[rr * 36 + c8]) = v0;
            *reinterpret_cast<float4*>(&linT[rr * 36 + c8 + 4]) = v1;
        }

        // --- inter-block contribution GEMM (K = 32b), history from registers ---
        f32x4 accC[2];
        accC[0] = (f32x4){0.f, 0.f, 0.f, 0.f};
        accC[1] = (f32x4){0.f, 0.f, 0.f, 0.f};
        #pragma unroll
        for (int kc = 0; kc < 7; ++kc) {
            if (kc < b) {
                f16x8 ah = hh[kc];
                f16x8 al = ll[kc];
                #pragma unroll
                for (int n2 = 0; n2 < 2; ++n2) {
                    const size_t wrow = (size_t)(b * 32 + n2 * 16 + l15 - 1) * 256 + kc * 32 + g * 8;
                    f16x8 bh = __builtin_bit_cast(f16x8, *reinterpret_cast<const u16x8*>(wnl_h + wrow));
                    f16x8 bl = __builtin_bit_cast(f16x8, *reinterpret_cast<const u16x8*>(wnl_l + wrow));
                    accC[n2] = __builtin_amdgcn_mfma_f32_16x16x32_f16(ah, bh, accC[n2], 0, 0, 0);
                    accC[n2] = __builtin_amdgcn_mfma_f32_16x16x32_f16(al, bh, accC[n2], 0, 0, 0);
                    accC[n2] = __builtin_amdgcn_mfma_f32_16x16x32_f16(ah, bl, accC[n2], 0, 0, 0);
                }
            }
        }
        // bounce D-frags -> conT[row][col]
        #pragma unroll
        for (int n2 = 0; n2 < 2; ++n2)
            #pragma unroll
            for (int j = 0; j < 4; ++j)
                conT[(g * 4 + j) * 36 + n2 * 16 + l15] = accC[n2][j];
        __syncthreads();

        if (b == 0) carry = linT[l15 * 36];   // lin[row, 0] for neuron 0

        // --- serial 32 steps; all operands registers / scalar loads ---
        float lastlin = carry;
        #pragma unroll
        for (int u8 = 0; u8 < 4; ++u8) {
            float4 cw0 = *reinterpret_cast<const float4*>(&conT[l15 * 36 + u8 * 8]);
            float4 cw1 = *reinterpret_cast<const float4*>(&conT[l15 * 36 + u8 * 8 + 4]);
            float4 lw0 = *reinterpret_cast<const float4*>(&linT[l15 * 36 + u8 * 8]);
            float4 lw1 = *reinterpret_cast<const float4*>(&linT[l15 * 36 + u8 * 8 + 4]);
            float conw[8] = {cw0.x, cw0.y, cw0.z, cw0.w, cw1.x, cw1.y, cw1.z, cw1.w};
            float linw[8] = {lw0.x, lw0.y, lw0.z, lw0.w, lw1.x, lw1.y, lw1.z, lw1.w};
            #pragma unroll
            for (int v = 0; v < 8; ++v) {
                const int u = u8 * 8 + v;
                float pa = 0.0f;
                if (u > 0) {
                    // compact triangular slab, contiguous, uniform address -> s_load
                    const float* wr = wtri + b * 496 + (u * (u - 1)) / 2;
                    float p0 = 0.f, p1 = 0.f, p2 = 0.f, p3 = 0.f;
                    #pragma unroll
                    for (int c = 0; c + 3 < u; c += 4) {
                        p0 = fmaf(th[c],     wr[c],     p0);
                        p1 = fmaf(th[c + 1], wr[c + 1], p1);
                        p2 = fmaf(th[c + 2], wr[c + 2], p2);
                        p3 = fmaf(th[c + 3], wr[c + 3], p3);
                    }
                    #pragma unroll
                    for (int c = u & ~3; c < u; ++c)
                        p0 = fmaf(th[c], wr[c], p0);
                    pa = (p0 + p1) + (p2 + p3);
                }
                float lv = (v == 0) ? lastlin : linw[v - 1];
                float vv = pa + conw[v] + lv + 1.0f;
                th[u] = fast_tanh(vv);
            }
            lastlin = linw[7];
        }
        carry = lastlin;

        // --- pack history via LDS bounce (g-slice needs cross-lane transpose) ---
        __syncthreads();
        if (l < 16) {
            #pragma unroll
            for (int c8 = 0; c8 < 32; c8 += 4)
                *reinterpret_cast<float4*>(&conT[l15 * 36 + c8]) =
                    (float4){th[c8], th[c8 + 1], th[c8 + 2], th[c8 + 3]};
        }
        __syncthreads();
        float4 s0 = *reinterpret_cast<const float4*>(&conT[l15 * 36 + g * 8]);
        float4 s1 = *reinterpret_cast<const float4*>(&conT[l15 * 36 + g * 8 + 4]);
        float sv[8] = {s0.x, s0.y, s0.z, s0.w, s1.x, s1.y, s1.z, s1.w};
        f16x8 fh, fl;
        #pragma unroll
        for (int e = 0; e < 8; ++e) {
            _Float16 hv = (_Float16)sv[e];
            fh[e] = hv;
            fl[e] = (_Float16)(sv[e] - (float)hv);
        }
        hh[b] = fh;
        ll[b] = fl;
        __syncthreads();
    }

    // ===== stage 3: out = tanh @ W_out^T + lin_o + 1 =====
    #pragma unroll
    for (int n = 0; n < 4; ++n) {
        f32x4 acc = (f32x4){0.f, 0.f, 0.f, 0.f};
        #pragma unroll
        for (int kc = 0; kc < 8; ++kc) {
            const size_t wrow = (size_t)(n * 16 + l15) * 256 + kc * 32 + g * 8;
            f16x8 bh = __builtin_bit_cast(f16x8, *reinterpret_cast<const u16x8*>(wout_h + wrow));
            f16x8 bl = __builtin_bit_cast(f16x8, *reinterpret_cast<const u16x8*>(wout_l + wrow));
            acc = __builtin_amdgcn_mfma_f32_16x16x32_f16(hh[kc], bh, acc, 0, 0, 0);
            acc = __builtin_amdgcn_mfma_f32_16x16x32_f16(ll[kc], bh, acc, 0, 0, 0);
            acc = __builtin_amdgcn_mfma_f32_16x16x32_f16(hh[kc], bl, acc, 0, 0, 0);
        }
        #pragma unroll
        for (int j = 0; j < 4; ++j) {
            long r = row0 + g * 4 + j;
            int c = n * 16 + l15;
            out[r * 64 + c] = acc[j] + lino[r * 64 + c] + 1.0f;
        }
    }
}

extern "C" void kernel_launch(void* const* d_in, const int* in_sizes, int n_in,
                              void* d_out, int out_size, void* d_ws, size_t ws_size,
                              hipStream_t stream) {
    (void)in_sizes; (void)n_in; (void)out_size; (void)ws_size;
    const float* x     = (const float*)d_in[0];
    const float* W_lin = (const float*)d_in[1];
    const float* W_nl  = (const float*)d_in[2];
    const float* W_out = (const float*)d_in[3];
    float* out = (float*)d_out;

    char* ws = (char*)d_ws;
    unsigned short* wlin_h = (unsigned short*)(ws);
    unsigned short* wlin_l = (unsigned short*)(ws + 327680);
    float*          wnlm   = (float*)(ws + 655360);
    unsigned short* wnl_h  = (unsigned short*)(ws + 916480);
    unsigned short* wnl_l  = (unsigned short*)(ws + 1047040);
    unsigned short* wout_h = (unsigned short*)(ws + 1177600);
    unsigned short* wout_l = (unsigned short*)(ws + 1210368);
    float*          wtri   = (float*)(ws + 1243136);
    float*          linc   = (float*)(ws + 1259008);
    float*          lino   = (float*)(ws + 68367872);

    cascade_prep<<<256, 256, 0, stream>>>(W_lin, W_nl, W_out,
                                          wlin_h, wlin_l, wnlm, wnl_h, wnl_l,
                                          wout_h, wout_l, wtri);
    lin_gemm<<<65536 / 32, 256, 0, stream>>>(x, wlin_h, wlin_l, linc, lino);
    cascade_casc<<<65536 / 16, 64, 0, stream>>>(linc, lino, wtri,
                                                wnl_h, wnl_l, wout_h, wout_l, out);
}